// Round 8
// baseline (4778.048 us; speedup 1.0000x reference)
//
#include <hip/hip_runtime.h>

// ---------------------------------------------------------------------------
// Llama4TextExperts: per-expert  out = (up * silu(gate)) @ W2
// E=8, T=8192 (1024/expert), H=2048, I=4096, fp32 in/out, bf16 MFMA compute.
// R8: R6 (256x256x64 8-phase, f4 B loads, dual B reg-slots) with the LDS
//     write conflict fixed: staggered write order j=(s+(lane>>1))&3 makes
//     every 8-lane group of every ds access span 8 distinct 16B slots.
//     Empirical law from R3-R7: <8 distinct slots costs 12-25 cy/instr.
// ---------------------------------------------------------------------------

#define E_   8
#define H_   2048
#define I_   4096
#define T_   8192
#define TPE  1024

typedef __bf16 bf16x8 __attribute__((ext_vector_type(8)));
typedef float  f32x4  __attribute__((ext_vector_type(4)));

__device__ __forceinline__ unsigned short f2bf(float f) {
  union { float f; unsigned int u; } v; v.f = f;
  unsigned int u = v.u;
  u += 0x7FFFu + ((u >> 16) & 1u);   // RNE
  return (unsigned short)(u >> 16);
}

__device__ __forceinline__ void async16(const void* g, void* l) {
  __builtin_amdgcn_global_load_lds(
      (__attribute__((address_space(1))) void*)(g),
      (__attribute__((address_space(3))) void*)(l), 16, 0, 0);
}

#define SB0()      __builtin_amdgcn_sched_barrier(0)
#define BAR()      __builtin_amdgcn_s_barrier()
#define WAITLGKM() asm volatile("s_waitcnt lgkmcnt(0)" ::: "memory")
#define WAITVM(n)  asm volatile("s_waitcnt vmcnt(" #n ")" ::: "memory")

// ---------------------------------------------------------------------------
__global__ void convert_bf16(const float* __restrict__ src,
                             unsigned short* __restrict__ dst, long n) {
  long i = ((long)blockIdx.x * blockDim.x + threadIdx.x) * 4;
  const long stride = (long)gridDim.x * blockDim.x * 4;
  for (; i < n; i += stride) {
    const float4 v = *(const float4*)&src[i];
    ushort4 o;
    o.x = f2bf(v.x); o.y = f2bf(v.y); o.z = f2bf(v.z); o.w = f2bf(v.w);
    *(ushort4*)&dst[i] = o;
  }
}

// ---------------------------------------------------------------------------
// 256x256x64 8-phase GEMM. A: bf16 (M,K) via global_load_lds (linear dest,
// pre-swizzled source; LDS slot s of row r holds k-octet s^(r&7)).
// B: fp32 (K,N); lane owns storage rows 4*lane..+3 (= 4 contiguous global
// cols), wave owns k-octet; 8 float4 loads -> reg transpose -> 4x
// ds_write_b128 in STAGGERED order j=(s+(lane>>1))&3 at slot wave^(st&7):
// each write instr's 8-lane group spans st&7 = {s..s+3 mod 4} u {4+..} = 8
// distinct slots (conflict-free). Reads (A and B) use key lr&7 (8 distinct).
// vmcnt ledger (per-thread FIFO, per tile):
//   P1 issues A q0(t+2) [2] | P2: WAITVM(4) retires B(t+1)(+q0(t+1), landed),
//   WRITEB B(t+1), LOADB B(t+2) [8] | P3 issues A q1(t+2) [2], WAITVM(12)
//   retires q1(t+1). Cover >= 4 phases for every staged unit.
// LDS 128KB: A[2][256][64] bf16 + B[2][256][64] bf16.
// ---------------------------------------------------------------------------
template <int K, int NBN, int LDB, bool SILU>
__global__ __launch_bounds__(512, 2)
void gemm_fused(const unsigned short* __restrict__ Aall,
                const float* __restrict__ Ball,
                void* __restrict__ Cout,
                long sA, long sB, long sC) {
  extern __shared__ char smem[];
  constexpr int NT = K / 64;
  static_assert(NT % 2 == 0, "NT must be even for the x2 unroll");

  const int tid  = threadIdx.x;
  const int wave = tid >> 6;
  const int lane = tid & 63;
  const int lr   = lane & 15;
  const int lq   = lane >> 4;
  const int wid_m = wave >> 2;     // 0..1
  const int wid_n = wave & 3;      // 0..3

  // T1: bijective XCD swizzle (gridDim.x % 8 == 0), mb innermost.
  const int nwg = gridDim.x;
  const int bid = blockIdx.x;
  const int wg  = (bid & 7) * (nwg >> 3) + (bid >> 3);
  const int mb  = wg & 3;
  const int tmp = wg >> 2;
  const int nb  = tmp % NBN;
  const int e   = tmp / NBN;

  const unsigned short* A = Aall + (long)e * sA + (long)(mb * 256) * K;
  const float*          B = Ball + (long)e * sB;

  // ---- A staging (global_load_lds, pre-swizzled source) ------------------
  const int stl  = tid >> 3;                      // 0..63
  const int scol = ((tid & 7) ^ (stl & 7)) * 8;   // swizzled src elem col

  auto stageA = [&](int bi, int q, int kt) {
    const long col = (long)kt * 64 + scol;
    char* l0 = smem + bi * 32768 + q * 16384 + wave * 1024;
    async16(A + (long)(q * 64 + stl) * K + col,        l0);
    async16(A + (long)(128 + q * 64 + stl) * K + col,  l0 + 8192);
  };

  // ---- B: lane owns storage rows 4*lane..4*lane+3 (contiguous global cols),
  //         wave owns k-octet ko=wave. 8 float4 loads per tile.
  int colq;   // global col of storage row st = 4*lane (quad is contiguous)
  {
    const int st = 4 * lane;
    const int b  = st >> 7;
    const int r  = st & 127;
    const int w  = r >> 5;
    const int nf = (r >> 4) & 1;
    const int l4 = st & 15;
    if (SILU) colq = nb * 128 + (w * 32 + b * 16 + l4) + (nf ? I_ : 0);
    else      colq = nb * 256 + w * 64 + (b * 2 + nf) * 16 + l4;
  }
  const float* Bq = B + colq;

  f32x4 bvA[8], bvB[8];

  auto LOADB = [&](auto& bv, int kt) {
    const long kbase = (long)kt * 64 + wave * 8;
#pragma unroll
    for (int i = 0; i < 8; ++i)
      bv[i] = *(const f32x4*)&Bq[(kbase + i) * (long)LDB];
  };
  // Staggered conflict-free write: instr s writes j=(s+(lane>>1))&3.
  // 8-lane group: st&7 = {s,s+1,s+2,s+3 (mod4)} u {4+same} = 8 distinct.
  auto WRITEB = [&](int bo, auto& bv) {
    char* LBw = smem + 65536 + bo * 32768;
#pragma unroll
    for (int s = 0; s < 4; ++s) {
      const int j = (s + (lane >> 1)) & 3;
      bf16x8 pk;
#pragma unroll
      for (int i = 0; i < 8; ++i) pk[i] = (__bf16)bv[i][j];
      const int st = 4 * lane + j;
      *(bf16x8*)(LBw + st * 128 + ((wave ^ (st & 7)) * 16)) = pk;
    }
  };

  // fragment-read swizzled slot offsets (key = lr&7 for both A and B)
  const int ax0 = ((0 + lq) ^ (lr & 7)) * 16;    // k 0..31
  const int ax1 = ((4 + lq) ^ (lr & 7)) * 16;    // k 32..63

  f32x4 acc[8][4];
#pragma unroll
  for (int m = 0; m < 8; ++m)
#pragma unroll
    for (int n = 0; n < 4; ++n) acc[m][n] = (f32x4)0.0f;

  // ---------------- prologue --------------------------------------------
  const int t1p = (NT > 1) ? 1 : 0;
  LOADB(bvA, 0);               // 8: B(0)
  stageA(0, 0, 0);             // 2
  stageA(0, 1, 0);             // 2
  SB0();
  WAITVM(4); SB0();            // B(0) regs ready (leaves A(0) 4)
  WRITEB(0, bvA);              // B(0) -> buf0
  WAITLGKM(); SB0();           // publish B(0) before prologue barrier
  stageA(1, 0, t1p); SB0();    // 2  q0(1)
  LOADB(bvB, t1p); SB0();      // 8  B(1)
  stageA(1, 1, t1p); SB0();    // 2  q1(1)
  WAITVM(12); SB0();           // drain A(0); leaves [q0(1)2, B(1)8, q1(1)2]
  BAR();

  // ---------------- tile body (bvW holds B(t+1); bvL gets B(t+2)) --------
  auto body = [&](int t, auto& bvW, auto& bvL) {
    const int cur = t & 1;
    const int bo  = cur ^ 1;
    const char* LA = smem + cur * 32768;
    const char* LB = smem + 65536 + cur * 32768;
    const int t2v = (t + 2 < NT) ? t + 2 : NT - 1;

    bf16x8 a[4][2], b0[2][2], b1[2][2];

    // ---- P0: read a(q0)+b0; no VMEM ------------------------------------
#pragma unroll
    for (int mf = 0; mf < 4; ++mf) {
      const int st = wid_m * 64 + mf * 16 + lr;
      a[mf][0] = *(const bf16x8*)(LA + st * 128 + ax0);
      a[mf][1] = *(const bf16x8*)(LA + st * 128 + ax1);
    }
#pragma unroll
    for (int nf = 0; nf < 2; ++nf) {
      const int st = wid_n * 32 + nf * 16 + lr;
      b0[nf][0] = *(const bf16x8*)(LB + st * 128 + ax0);
      b0[nf][1] = *(const bf16x8*)(LB + st * 128 + ax1);
    }
    SB0();
    BAR();
    WAITLGKM(); SB0();
    __builtin_amdgcn_s_setprio(1);
#pragma unroll
    for (int mf = 0; mf < 4; ++mf)
#pragma unroll
      for (int nf = 0; nf < 2; ++nf) {
        acc[mf][nf] = __builtin_amdgcn_mfma_f32_16x16x32_bf16(a[mf][0], b0[nf][0], acc[mf][nf], 0, 0, 0);
        acc[mf][nf] = __builtin_amdgcn_mfma_f32_16x16x32_bf16(a[mf][1], b0[nf][1], acc[mf][nf], 0, 0, 0);
      }
    __builtin_amdgcn_s_setprio(0);
    BAR();

    // ---- P1: read b1; issue A(t+2)q0 -----------------------------------
#pragma unroll
    for (int nf = 0; nf < 2; ++nf) {
      const int st = 128 + wid_n * 32 + nf * 16 + lr;
      b1[nf][0] = *(const bf16x8*)(LB + st * 128 + ax0);
      b1[nf][1] = *(const bf16x8*)(LB + st * 128 + ax1);
    }
    stageA(cur, 0, t2v);
    SB0();
    BAR();
    WAITLGKM(); SB0();
    __builtin_amdgcn_s_setprio(1);
#pragma unroll
    for (int mf = 0; mf < 4; ++mf)
#pragma unroll
      for (int nf = 0; nf < 2; ++nf) {
        acc[mf][2 + nf] = __builtin_amdgcn_mfma_f32_16x16x32_bf16(a[mf][0], b1[nf][0], acc[mf][2 + nf], 0, 0, 0);
        acc[mf][2 + nf] = __builtin_amdgcn_mfma_f32_16x16x32_bf16(a[mf][1], b1[nf][1], acc[mf][2 + nf], 0, 0, 0);
      }
    __builtin_amdgcn_s_setprio(0);
    BAR();

    // ---- P2: read a(q1); WAITVM(4) -> WRITEB B(t+1); LOADB B(t+2) ------
#pragma unroll
    for (int mf = 0; mf < 4; ++mf) {
      const int st = 128 + wid_m * 64 + mf * 16 + lr;
      a[mf][0] = *(const bf16x8*)(LA + st * 128 + ax0);
      a[mf][1] = *(const bf16x8*)(LA + st * 128 + ax1);
    }
    SB0();
    WAITVM(4); SB0();          // retires B(t+1) (+q0(t+1), already landed)
    WRITEB(bo, bvW);
    LOADB(bvL, t2v);           // different reg slot: no WAR drain needed
    SB0();
    BAR();
    WAITLGKM(); SB0();         // a(q1) reads + own ds_writes drained
    __builtin_amdgcn_s_setprio(1);
#pragma unroll
    for (int mf = 0; mf < 4; ++mf)
#pragma unroll
      for (int nf = 0; nf < 2; ++nf) {
        acc[4 + mf][2 + nf] = __builtin_amdgcn_mfma_f32_16x16x32_bf16(a[mf][0], b1[nf][0], acc[4 + mf][2 + nf], 0, 0, 0);
        acc[4 + mf][2 + nf] = __builtin_amdgcn_mfma_f32_16x16x32_bf16(a[mf][1], b1[nf][1], acc[4 + mf][2 + nf], 0, 0, 0);
      }
    __builtin_amdgcn_s_setprio(0);
    BAR();

    // ---- P3: issue A(t+2)q1; WAITVM(12); MFMA on regs ------------------
    stageA(cur, 1, t2v);
    SB0();
    WAITVM(12); SB0();         // retires q1(t+1)
    BAR();
    __builtin_amdgcn_s_setprio(1);
#pragma unroll
    for (int mf = 0; mf < 4; ++mf)
#pragma unroll
      for (int nf = 0; nf < 2; ++nf) {
        acc[4 + mf][nf] = __builtin_amdgcn_mfma_f32_16x16x32_bf16(a[mf][0], b0[nf][0], acc[4 + mf][nf], 0, 0, 0);
        acc[4 + mf][nf] = __builtin_amdgcn_mfma_f32_16x16x32_bf16(a[mf][1], b0[nf][1], acc[4 + mf][nf], 0, 0, 0);
      }
    __builtin_amdgcn_s_setprio(0);
    BAR();
  };

#pragma unroll 1
  for (int tt = 0; tt < NT; tt += 2) {
    body(tt,     bvB, bvA);    // even t: write B(t+1) from bvB, load into bvA
    body(tt + 1, bvA, bvB);    // odd  t: write from bvA, load into bvB
  }

  WAITVM(0);                   // trailing clamped loads must not outlive LDS

  // ---------------- epilogue (C/D: col=lane&15, row=(lane>>4)*4+r) -------
  if (SILU) {
    unsigned short* Cc = (unsigned short*)Cout + (long)e * sC;
#pragma unroll
    for (int mf = 0; mf < 8; ++mf)
#pragma unroll
      for (int p = 0; p < 2; ++p)
#pragma unroll
        for (int rr = 0; rr < 4; ++rr) {
          const int row = mb * 256 + wid_m * 128 + mf * 16 + lq * 4 + rr;
          const int col = nb * 128 + wid_n * 32 + p * 16 + lr;
          const float g = acc[mf][p * 2][rr];
          const float u = acc[mf][p * 2 + 1][rr];
          Cc[(long)row * I_ + col] = f2bf(u * (g / (1.0f + __expf(-g))));
        }
  } else {
    float* Cc = (float*)Cout + (long)e * sC;
#pragma unroll
    for (int mf = 0; mf < 8; ++mf)
#pragma unroll
      for (int q = 0; q < 4; ++q)
#pragma unroll
        for (int rr = 0; rr < 4; ++rr) {
          const int row = mb * 256 + wid_m * 128 + mf * 16 + lq * 4 + rr;
          const int col = nb * 256 + wid_n * 64 + q * 16 + lr;
          Cc[(long)row * H_ + col] = acc[mf][q][rr];
        }
  }
}

// ---------------------------------------------------------------------------
extern "C" void kernel_launch(void* const* d_in, const int* in_sizes, int n_in,
                              void* d_out, int out_size, void* d_ws, size_t ws_size,
                              hipStream_t stream) {
  const float* hs = (const float*)d_in[0];   // (8192, 2048)
  const float* w1 = (const float*)d_in[1];   // (8, 2048, 8192)
  const float* w2 = (const float*)d_in[2];   // (8, 4096, 2048)
  float* out = (float*)d_out;                // (8192, 2048) fp32
  char* ws = (char*)d_ws;

  const long HB_B  = (long)T_ * H_ * 2;      // 32 MiB hidden bf16
  const long ACT_B = (long)T_ * I_ * 2;      // 64 MiB acted bf16
  if (ws_size < (size_t)(HB_B + ACT_B)) return;

  unsigned short* hiddenB = (unsigned short*)(ws);
  unsigned short* acted   = (unsigned short*)(ws + HB_B);

  hipLaunchKernelGGL(convert_bf16, dim3(2048), dim3(256), 0, stream,
                     hs, hiddenB, (long)T_ * H_);

  // gemm1+SiLU: A=hiddenB (TPE,H), B=W1 (H,2I) fp32 direct -> acted bf16
  hipLaunchKernelGGL((gemm_fused<H_, 32, 2 * I_, true>),
                     dim3(1024), dim3(512), 131072, stream,
                     hiddenB, w1, acted,
                     (long)TPE * H_, (long)H_ * 2 * I_, (long)TPE * I_);

  // gemm2: A=acted (TPE,I), B=W2 (I,H) fp32 direct -> out fp32
  hipLaunchKernelGGL((gemm_fused<I_, 8, H_, false>),
                     dim3(256), dim3(512), 131072, stream,
                     acted, w2, out,
                     (long)TPE * I_, (long)I_ * H_, (long)TPE * H_);
}

// Round 9
// 595.264 us; speedup vs baseline: 8.0268x; 8.0268x over previous
//
#include <hip/hip_runtime.h>

// ---------------------------------------------------------------------------
// Llama4TextExperts: per-expert  out = (up * silu(gate)) @ W2
// E=8, T=8192 (1024/expert), H=2048, I=4096, fp32 in/out, bf16 MFMA compute.
// R9: R6 structure with STATIC-index conflict-free B staging: lane owns 4
//     stride-64 storage rows (st = 64j+lane), so write slot wave^(lane&7)
//     is 8-distinct (R5's measured-clean write shape) AND read key st&7 =
//     lr&7 is 8-distinct (R3/R4's measured-clean read shape). No runtime
//     vector indexing anywhere (R8's rule-#20 scratch disaster fixed).
//     colOf(64j+lane)=cbase(lane)+j keeps f4 loads contiguous; epilogue
//     compensates the column permutation.
// ---------------------------------------------------------------------------

#define E_   8
#define H_   2048
#define I_   4096
#define T_   8192
#define TPE  1024

typedef __bf16 bf16x8 __attribute__((ext_vector_type(8)));
typedef float  f32x4  __attribute__((ext_vector_type(4)));

__device__ __forceinline__ unsigned short f2bf(float f) {
  union { float f; unsigned int u; } v; v.f = f;
  unsigned int u = v.u;
  u += 0x7FFFu + ((u >> 16) & 1u);   // RNE
  return (unsigned short)(u >> 16);
}

__device__ __forceinline__ void async16(const void* g, void* l) {
  __builtin_amdgcn_global_load_lds(
      (__attribute__((address_space(1))) void*)(g),
      (__attribute__((address_space(3))) void*)(l), 16, 0, 0);
}

#define SB0()      __builtin_amdgcn_sched_barrier(0)
#define BAR()      __builtin_amdgcn_s_barrier()
#define WAITLGKM() asm volatile("s_waitcnt lgkmcnt(0)" ::: "memory")
#define WAITVM(n)  asm volatile("s_waitcnt vmcnt(" #n ")" ::: "memory")

// ---------------------------------------------------------------------------
__global__ void convert_bf16(const float* __restrict__ src,
                             unsigned short* __restrict__ dst, long n) {
  long i = ((long)blockIdx.x * blockDim.x + threadIdx.x) * 4;
  const long stride = (long)gridDim.x * blockDim.x * 4;
  for (; i < n; i += stride) {
    const float4 v = *(const float4*)&src[i];
    ushort4 o;
    o.x = f2bf(v.x); o.y = f2bf(v.y); o.z = f2bf(v.z); o.w = f2bf(v.w);
    *(ushort4*)&dst[i] = o;
  }
}

// ---------------------------------------------------------------------------
// 256x256x64 8-phase GEMM. A: bf16 (M,K) via global_load_lds (linear dest,
// pre-swizzled source; LDS slot s of row r holds k-octet s^(r&7)).
// B: fp32 (K,N); lane owns storage rows {64j+lane}, j=0..3, mapping to 4
// CONTIGUOUS global cols cbase(lane)+j; wave owns k-octet. 8 float4 loads
// -> reg transpose -> 4x ds_write_b128 (j static) at slot wave^(lane&7):
// 8 distinct slots per 8-lane group on writes AND reads (key lr&7).
//   SILU:  cbase(lane)= nb*128 + (lane>>5)*64 + (lane&15)*4 + ((lane>>4)&1)*I_
//   plain: cbase(lane)= nb*256 + lane*4
// Epilogue inverse: col j-part = st>>6, lane-part = st&63.
// vmcnt ledger (per-thread FIFO, per tile) — identical to R6 (passed 2x):
//   P1 issues A q0(t+2) [2] | P2: WAITVM(4) retires B(t+1), WRITEB B(t+1),
//   LOADB B(t+2) [8] | P3 issues A q1(t+2) [2], WAITVM(12) retires q1(t+1).
// LDS 128KB: A[2][256][64] bf16 + B[2][256][64] bf16.
// ---------------------------------------------------------------------------
template <int K, int NBN, int LDB, bool SILU>
__global__ __launch_bounds__(512, 2)
void gemm_fused(const unsigned short* __restrict__ Aall,
                const float* __restrict__ Ball,
                void* __restrict__ Cout,
                long sA, long sB, long sC) {
  extern __shared__ char smem[];
  constexpr int NT = K / 64;
  static_assert(NT % 2 == 0, "NT must be even for the x2 unroll");

  const int tid  = threadIdx.x;
  const int wave = tid >> 6;
  const int lane = tid & 63;
  const int lr   = lane & 15;
  const int lq   = lane >> 4;
  const int wid_m = wave >> 2;     // 0..1
  const int wid_n = wave & 3;      // 0..3

  // T1: bijective XCD swizzle (gridDim.x % 8 == 0), mb innermost.
  const int nwg = gridDim.x;
  const int bid = blockIdx.x;
  const int wg  = (bid & 7) * (nwg >> 3) + (bid >> 3);
  const int mb  = wg & 3;
  const int tmp = wg >> 2;
  const int nb  = tmp % NBN;
  const int e   = tmp / NBN;

  const unsigned short* A = Aall + (long)e * sA + (long)(mb * 256) * K;
  const float*          B = Ball + (long)e * sB;

  // ---- A staging (global_load_lds, pre-swizzled source) ------------------
  const int stl  = tid >> 3;                      // 0..63
  const int scol = ((tid & 7) ^ (stl & 7)) * 8;   // swizzled src elem col

  auto stageA = [&](int bi, int q, int kt) {
    const long col = (long)kt * 64 + scol;
    char* l0 = smem + bi * 32768 + q * 16384 + wave * 1024;
    async16(A + (long)(q * 64 + stl) * K + col,        l0);
    async16(A + (long)(128 + q * 64 + stl) * K + col,  l0 + 8192);
  };

  // ---- B: lane owns storage rows {64j+lane} = global cols cbase+j --------
  int cbase;
  if (SILU) {
    cbase = nb * 128 + (lane >> 5) * 64 + (lane & 15) * 4
          + (((lane >> 4) & 1) ? I_ : 0);
  } else {
    cbase = nb * 256 + lane * 4;
  }
  const float* Bq = B + cbase;

  f32x4 bvA[8], bvB[8];

  auto LOADB = [&](auto& bv, int kt) {
    const long kbase = (long)kt * 64 + wave * 8;
#pragma unroll
    for (int i = 0; i < 8; ++i)
      bv[i] = *(const f32x4*)&Bq[(kbase + i) * (long)LDB];
  };
  // j static; st = 64j+lane; slot = wave^(st&7) = wave^(lane&7) (constant).
  auto WRITEB = [&](int bo, auto& bv) {
    char* LBw = smem + 65536 + bo * 32768 + ((wave ^ (lane & 7)) * 16);
#pragma unroll
    for (int j = 0; j < 4; ++j) {
      bf16x8 pk;
#pragma unroll
      for (int i = 0; i < 8; ++i) pk[i] = (__bf16)bv[i][j];
      *(bf16x8*)(LBw + (64 * j + lane) * 128) = pk;
    }
  };

  // fragment-read swizzled slot offsets (key = lr&7 for both A and B)
  const int ax0 = ((0 + lq) ^ (lr & 7)) * 16;    // k 0..31
  const int ax1 = ((4 + lq) ^ (lr & 7)) * 16;    // k 32..63

  f32x4 acc[8][4];
#pragma unroll
  for (int m = 0; m < 8; ++m)
#pragma unroll
    for (int n = 0; n < 4; ++n) acc[m][n] = (f32x4)0.0f;

  // ---------------- prologue --------------------------------------------
  const int t1p = (NT > 1) ? 1 : 0;
  LOADB(bvA, 0);               // 8: B(0)
  stageA(0, 0, 0);             // 2
  stageA(0, 1, 0);             // 2
  SB0();
  WAITVM(4); SB0();            // B(0) regs ready (leaves A(0) 4)
  WRITEB(0, bvA);              // B(0) -> buf0
  WAITLGKM(); SB0();           // publish B(0) before prologue barrier
  stageA(1, 0, t1p); SB0();    // 2  q0(1)
  LOADB(bvB, t1p); SB0();      // 8  B(1)
  stageA(1, 1, t1p); SB0();    // 2  q1(1)
  WAITVM(12); SB0();           // drain A(0); leaves [q0(1)2, B(1)8, q1(1)2]
  BAR();

  // ---------------- tile body (bvW holds B(t+1); bvL gets B(t+2)) --------
  auto body = [&](int t, auto& bvW, auto& bvL) {
    const int cur = t & 1;
    const int bo  = cur ^ 1;
    const char* LA = smem + cur * 32768;
    const char* LB = smem + 65536 + cur * 32768;
    const int t2v = (t + 2 < NT) ? t + 2 : NT - 1;

    bf16x8 a[4][2], b0[2][2], b1[2][2];

    // ---- P0: read a(q0)+b0; no VMEM ------------------------------------
#pragma unroll
    for (int mf = 0; mf < 4; ++mf) {
      const int st = wid_m * 64 + mf * 16 + lr;
      a[mf][0] = *(const bf16x8*)(LA + st * 128 + ax0);
      a[mf][1] = *(const bf16x8*)(LA + st * 128 + ax1);
    }
#pragma unroll
    for (int nf = 0; nf < 2; ++nf) {
      const int st = wid_n * 32 + nf * 16 + lr;
      b0[nf][0] = *(const bf16x8*)(LB + st * 128 + ax0);
      b0[nf][1] = *(const bf16x8*)(LB + st * 128 + ax1);
    }
    SB0();
    BAR();
    WAITLGKM(); SB0();
    __builtin_amdgcn_s_setprio(1);
#pragma unroll
    for (int mf = 0; mf < 4; ++mf)
#pragma unroll
      for (int nf = 0; nf < 2; ++nf) {
        acc[mf][nf] = __builtin_amdgcn_mfma_f32_16x16x32_bf16(a[mf][0], b0[nf][0], acc[mf][nf], 0, 0, 0);
        acc[mf][nf] = __builtin_amdgcn_mfma_f32_16x16x32_bf16(a[mf][1], b0[nf][1], acc[mf][nf], 0, 0, 0);
      }
    __builtin_amdgcn_s_setprio(0);
    BAR();

    // ---- P1: read b1; issue A(t+2)q0 -----------------------------------
#pragma unroll
    for (int nf = 0; nf < 2; ++nf) {
      const int st = 128 + wid_n * 32 + nf * 16 + lr;
      b1[nf][0] = *(const bf16x8*)(LB + st * 128 + ax0);
      b1[nf][1] = *(const bf16x8*)(LB + st * 128 + ax1);
    }
    stageA(cur, 0, t2v);
    SB0();
    BAR();
    WAITLGKM(); SB0();
    __builtin_amdgcn_s_setprio(1);
#pragma unroll
    for (int mf = 0; mf < 4; ++mf)
#pragma unroll
      for (int nf = 0; nf < 2; ++nf) {
        acc[mf][2 + nf] = __builtin_amdgcn_mfma_f32_16x16x32_bf16(a[mf][0], b1[nf][0], acc[mf][2 + nf], 0, 0, 0);
        acc[mf][2 + nf] = __builtin_amdgcn_mfma_f32_16x16x32_bf16(a[mf][1], b1[nf][1], acc[mf][2 + nf], 0, 0, 0);
      }
    __builtin_amdgcn_s_setprio(0);
    BAR();

    // ---- P2: read a(q1); WAITVM(4) -> WRITEB B(t+1); LOADB B(t+2) ------
#pragma unroll
    for (int mf = 0; mf < 4; ++mf) {
      const int st = 128 + wid_m * 64 + mf * 16 + lr;
      a[mf][0] = *(const bf16x8*)(LA + st * 128 + ax0);
      a[mf][1] = *(const bf16x8*)(LA + st * 128 + ax1);
    }
    SB0();
    WAITVM(4); SB0();          // retires B(t+1) (+q0(t+1), already landed)
    WRITEB(bo, bvW);
    LOADB(bvL, t2v);           // different reg slot: no WAR drain needed
    SB0();
    BAR();
    WAITLGKM(); SB0();         // a(q1) reads + own ds_writes drained
    __builtin_amdgcn_s_setprio(1);
#pragma unroll
    for (int mf = 0; mf < 4; ++mf)
#pragma unroll
      for (int nf = 0; nf < 2; ++nf) {
        acc[4 + mf][2 + nf] = __builtin_amdgcn_mfma_f32_16x16x32_bf16(a[mf][0], b1[nf][0], acc[4 + mf][2 + nf], 0, 0, 0);
        acc[4 + mf][2 + nf] = __builtin_amdgcn_mfma_f32_16x16x32_bf16(a[mf][1], b1[nf][1], acc[4 + mf][2 + nf], 0, 0, 0);
      }
    __builtin_amdgcn_s_setprio(0);
    BAR();

    // ---- P3: issue A(t+2)q1; WAITVM(12); MFMA on regs ------------------
    stageA(cur, 1, t2v);
    SB0();
    WAITVM(12); SB0();         // retires q1(t+1)
    BAR();
    __builtin_amdgcn_s_setprio(1);
#pragma unroll
    for (int mf = 0; mf < 4; ++mf)
#pragma unroll
      for (int nf = 0; nf < 2; ++nf) {
        acc[4 + mf][nf] = __builtin_amdgcn_mfma_f32_16x16x32_bf16(a[mf][0], b0[nf][0], acc[4 + mf][nf], 0, 0, 0);
        acc[4 + mf][nf] = __builtin_amdgcn_mfma_f32_16x16x32_bf16(a[mf][1], b0[nf][1], acc[4 + mf][nf], 0, 0, 0);
      }
    __builtin_amdgcn_s_setprio(0);
    BAR();
  };

#pragma unroll 1
  for (int tt = 0; tt < NT; tt += 2) {
    body(tt,     bvB, bvA);    // even t: write B(t+1) from bvB, load into bvA
    body(tt + 1, bvA, bvB);    // odd  t: write from bvA, load into bvB
  }

  WAITVM(0);                   // trailing clamped loads must not outlive LDS

  // ---------------- epilogue (C/D: col=lane&15, row=(lane>>4)*4+r) -------
  // B storage col inverse: st = p*128 + wid_n*32 + h*16 + lr
  //   j-part = (st>>6) = 2p + (wid_n>>1); lane-part = (wid_n&1)*32 + h*16 + lr
  if (SILU) {
    unsigned short* Cc = (unsigned short*)Cout + (long)e * sC;
#pragma unroll
    for (int mf = 0; mf < 8; ++mf)
#pragma unroll
      for (int p = 0; p < 2; ++p)
#pragma unroll
        for (int rr = 0; rr < 4; ++rr) {
          const int row = mb * 256 + wid_m * 128 + mf * 16 + lq * 4 + rr;
          const int col = nb * 128 + (wid_n & 1) * 64 + lr * 4
                        + 2 * p + (wid_n >> 1);
          const float g = acc[mf][p * 2][rr];       // h=0 half
          const float u = acc[mf][p * 2 + 1][rr];   // h=1 half, same acted col
          Cc[(long)row * I_ + col] = f2bf(u * (g / (1.0f + __expf(-g))));
        }
  } else {
    float* Cc = (float*)Cout + (long)e * sC;
#pragma unroll
    for (int mf = 0; mf < 8; ++mf)
#pragma unroll
      for (int q = 0; q < 4; ++q)
#pragma unroll
        for (int rr = 0; rr < 4; ++rr) {
          const int row = mb * 256 + wid_m * 128 + mf * 16 + lq * 4 + rr;
          const int lp  = (wid_n & 1) * 32 + (q & 1) * 16 + lr;
          const int col = nb * 256 + lp * 4 + (q >> 1) * 2 + (wid_n >> 1);
          Cc[(long)row * H_ + col] = acc[mf][q][rr];
        }
  }
}

// ---------------------------------------------------------------------------
extern "C" void kernel_launch(void* const* d_in, const int* in_sizes, int n_in,
                              void* d_out, int out_size, void* d_ws, size_t ws_size,
                              hipStream_t stream) {
  const float* hs = (const float*)d_in[0];   // (8192, 2048)
  const float* w1 = (const float*)d_in[1];   // (8, 2048, 8192)
  const float* w2 = (const float*)d_in[2];   // (8, 4096, 2048)
  float* out = (float*)d_out;                // (8192, 2048) fp32
  char* ws = (char*)d_ws;

  const long HB_B  = (long)T_ * H_ * 2;      // 32 MiB hidden bf16
  const long ACT_B = (long)T_ * I_ * 2;      // 64 MiB acted bf16
  if (ws_size < (size_t)(HB_B + ACT_B)) return;

  unsigned short* hiddenB = (unsigned short*)(ws);
  unsigned short* acted   = (unsigned short*)(ws + HB_B);

  hipLaunchKernelGGL(convert_bf16, dim3(2048), dim3(256), 0, stream,
                     hs, hiddenB, (long)T_ * H_);

  // gemm1+SiLU: A=hiddenB (TPE,H), B=W1 (H,2I) fp32 direct -> acted bf16
  hipLaunchKernelGGL((gemm_fused<H_, 32, 2 * I_, true>),
                     dim3(1024), dim3(512), 131072, stream,
                     hiddenB, w1, acted,
                     (long)TPE * H_, (long)H_ * 2 * I_, (long)TPE * I_);

  // gemm2: A=acted (TPE,I), B=W2 (I,H) fp32 direct -> out fp32
  hipLaunchKernelGGL((gemm_fused<I_, 8, H_, false>),
                     dim3(256), dim3(512), 131072, stream,
                     acted, w2, out,
                     (long)TPE * I_, (long)I_ * H_, (long)TPE * H_);
}